// Round 1
// baseline (442.542 us; speedup 1.0000x reference)
//
#include <hip/hip_runtime.h>

// AdaptiveLayer: per-(b,f) sequential scan over T.
//   out[b,t,f] = max(x[b,t,f] - adapt, 0)
//   adapt      = (adapt + 0.1*out) * 0.9
// x: [B=32, T=512, F=4096] f32. adaptation: [1, F] f32 (initial state).
// Memory-bound: 268 MB in + 268 MB out -> ~85 us roofline at 6.3 TB/s.

#define AB 32
#define AT 512
#define AF 4096
#define ADAPT_RATE 0.1f
#define RECOVERY_RATE 0.1f

__global__ __launch_bounds__(256) void AdaptiveLayer_kernel(
    const float* __restrict__ x,
    const float* __restrict__ adaptation,
    float* __restrict__ out) {
    // One thread per (b, f) chain. Consecutive tids -> consecutive f:
    // coalesced 256B/wave loads at each t (stride F between t steps).
    const int tid = blockIdx.x * blockDim.x + threadIdx.x;   // 0 .. B*F-1
    const int b = tid >> 12;           // tid / F   (F = 4096)
    const int f = tid & (AF - 1);      // tid % F

    float adapt = adaptation[f];       // initial adaptation state (broadcast over b)

    const size_t base = (size_t)b * (size_t)AT * (size_t)AF + (size_t)f;
    const float* __restrict__ xp = x + base;
    float* __restrict__ op = out + base;

    // Unroll t by 8: hoist 8 independent loads ahead of the serial recurrence
    // so each wave keeps ~8 loads in flight (latency hiding at 2 waves/SIMD).
    #pragma unroll 1
    for (int t = 0; t < AT; t += 8) {
        float v[8];
        #pragma unroll
        for (int j = 0; j < 8; ++j) {
            v[j] = xp[(size_t)(t + j) * AF];
        }
        #pragma unroll
        for (int j = 0; j < 8; ++j) {
            float o = fmaxf(v[j] - adapt, 0.0f);
            op[(size_t)(t + j) * AF] = o;
            adapt = (adapt + ADAPT_RATE * o) * (1.0f - RECOVERY_RATE);
        }
    }
}

extern "C" void kernel_launch(void* const* d_in, const int* in_sizes, int n_in,
                              void* d_out, int out_size, void* d_ws, size_t ws_size,
                              hipStream_t stream) {
    const float* x          = (const float*)d_in[0];   // [B, T, F]
    const float* adaptation = (const float*)d_in[1];   // [1, F]
    float* out              = (float*)d_out;           // [B, T, F]

    const int n_chains = AB * AF;                      // 131072 threads
    const int block = 256;
    const int grid = n_chains / block;                 // 512 blocks

    AdaptiveLayer_kernel<<<grid, block, 0, stream>>>(x, adaptation, out);
}